// Round 3
// baseline (2219.161 us; speedup 1.0000x reference)
//
#include <hip/hip_runtime.h>
#include <cstdint>
#include <cstddef>

#define BS_  4096
#define A_   128
#define OBS_ 128
#define ACT_ 8
#define SD_  4096
#define E_   32
#define H1_  128
#define H2_  64
#define NJ_  4096  // E_*A_

typedef __attribute__((ext_vector_type(8))) short bf16x8;
typedef __attribute__((ext_vector_type(4))) float f32x4;

__device__ __forceinline__ unsigned short f2bf(float f) {
  uint32_t u = __builtin_bit_cast(uint32_t, f);
  u += 0x7fffu + ((u >> 16) & 1u);   // RNE
  return (unsigned short)(u >> 16);
}
__device__ __forceinline__ float bf2f(unsigned short s) {
  return __builtin_bit_cast(float, (uint32_t)s << 16);
}

// ============ prep: Wh1 transpose + states->bf16 + small-W pack, one launch ==
// blocks [0,16384): transpose Wh1 [4096][4096] fp32 -> Wh1T bf16
// blocks [16384,18432): states fp32 -> bf16 flat
// blocks [18432,18944): pack [Whb|Whf|Wv1|0]^T -> WsmT [128][4096] bf16
__global__ __launch_bounds__(256) void prep_kernel(
    const float* __restrict__ states, unsigned short* __restrict__ Sbf,
    const float* __restrict__ Wh1, unsigned short* __restrict__ Wh1T,
    const float* __restrict__ Whb, const float* __restrict__ Whf,
    const float* __restrict__ Wv1, unsigned short* __restrict__ WsmT) {
  __shared__ float tile[32][33];
  int bid = blockIdx.x;
  int t = threadIdx.x;
  if (bid < 16384) {
    int tx = t & 31, ty = t >> 5;
    int c0 = (bid & 127) * 32, r0 = (bid >> 7) * 32;
#pragma unroll
    for (int rr = ty; rr < 32; rr += 8)
      tile[rr][tx] = Wh1[(size_t)(r0 + rr) * NJ_ + c0 + tx];
    __syncthreads();
#pragma unroll
    for (int rr = ty; rr < 32; rr += 8)
      Wh1T[(size_t)(c0 + rr) * SD_ + r0 + tx] = f2bf(tile[tx][rr]);
  } else if (bid < 18432) {
    // 2048 blocks * 256 thr * 8 float4 == BS_*SD_/4 exactly
    int i = (bid - 16384) * 256 + t;
    const int stride = 2048 * 256;
#pragma unroll
    for (int l = 0; l < 8; ++l, i += stride) {
      float4 v = ((const float4*)states)[i];
      ushort4 o;
      o.x = f2bf(v.x); o.y = f2bf(v.y); o.z = f2bf(v.z); o.w = f2bf(v.w);
      ((ushort4*)Sbf)[i] = o;
    }
  } else {
    int k = bid - 18432;            // 0..511
    int s = k >> 7;                 // 0:Whb 1:Whf 2:Wv1 3:zero
    int r0 = (k & 127) * 32;
    int tx = t & 31, ty = t >> 5;
    if (s == 3) {
#pragma unroll
      for (int rr = ty; rr < 32; rr += 8)
        WsmT[(size_t)(96 + rr) * SD_ + r0 + tx] = 0;
    } else {
      const float* src = (s == 0) ? Whb : ((s == 1) ? Whf : Wv1);
#pragma unroll
      for (int rr = ty; rr < 32; rr += 8)
        tile[rr][tx] = src[(size_t)(r0 + rr) * E_ + tx];
      __syncthreads();
#pragma unroll
      for (int rr = ty; rr < 32; rr += 8)
        WsmT[(size_t)(s * 32 + rr) * SD_ + r0 + tx] = f2bf(tile[tx][rr]);
    }
  }
}

// ---------------- per-agent MLP (fp32 exact; argmax-critical) ----------------
// 8192 blocks, 1 agent x 64 rows. LDS 49664 B -> 3 blocks/CU (12 waves).
// W1/W2 staged in 16 KB k-chunks with T14 async-stage: global->reg issued
// BEFORE the previous chunk's compute, reg->LDS after the drain barrier.
// Summation order identical to the verified kernel (bit-exact argmax).
__global__ __launch_bounds__(256) void mlp_kernel(
    const float* __restrict__ obs,
    const float* __restrict__ W1, const float* __restrict__ b1,
    const float* __restrict__ W2, const float* __restrict__ b2,
    const float* __restrict__ W3, const float* __restrict__ b3,
    float* __restrict__ agent_qs, float* __restrict__ actions_out) {
  __shared__ __align__(16) char smem[49664];
  float* As = (float*)smem;            // [64][130] = 33280 B
  float* Ws = (float*)(smem + 33280);  // 16 KB chunk buffer
  int idx = blockIdx.x;
  int a  = idx & (A_ - 1);
  int bt = idx >> 7;
  int b0 = bt * 64;
  int t  = threadIdx.x;
  int tx = t & 15, ty = t >> 4;

  // stage obs tile [64][128] (coalesced 512B rows); stride 130 (==2 mod 32)
  {
    const float* src = obs + ((size_t)b0 * A_ + a) * OBS_;
#pragma unroll
    for (int l = 0; l < 8; ++l) {
      int i2 = t + l * 256;
      int r = i2 >> 5, c4 = i2 & 31;
      *(float4*)&As[r * 130 + c4 * 4] =
          *(const float4*)(src + (size_t)r * (A_ * OBS_) + c4 * 4);
    }
  }

  const float* W1a = W1 + (size_t)a * OBS_ * H1_;
  const float* W2a = W2 + (size_t)a * H1_ * H2_;

  // W1 chunk 0 -> Ws directly (nothing to overlap; first barrier publishes)
#pragma unroll
  for (int l = 0; l < 4; ++l) {
    int i2 = t + l * 256;
    int kr = i2 >> 5, c4 = i2 & 31;
    *(float4*)&Ws[kr * 128 + c4 * 4] =
        *(const float4*)(W1a + (size_t)kr * H1_ + c4 * 4);
  }

  float acc[4][8];
#pragma unroll
  for (int i = 0; i < 4; ++i)
#pragma unroll
    for (int j = 0; j < 8; ++j) acc[i][j] = 0.f;

  // layer 1: [64x128]@[128x128], four 32-row chunks, prefetched
  float4 pre[4];   // after the loop holds W2 chunk 0
  for (int h = 0; h < 4; ++h) {
    if (h < 3) {
#pragma unroll
      for (int l = 0; l < 4; ++l) {           // prefetch W1 chunk h+1
        int i2 = t + l * 256;
        int kr = i2 >> 5, c4 = i2 & 31;
        pre[l] = *(const float4*)(W1a + (size_t)((h + 1) * 32 + kr) * H1_ + c4 * 4);
      }
    } else {
#pragma unroll
      for (int l = 0; l < 4; ++l) {           // prefetch W2 rows [0,64)
        int i2 = t + l * 256;
        int kr = i2 >> 4, c4 = i2 & 15;
        pre[l] = *(const float4*)(W2a + (size_t)kr * H2_ + c4 * 4);
      }
    }
    __syncthreads();                          // publish Ws (and As on h==0)
    for (int k0 = 0; k0 < 32; k0 += 4) {
      float4 av[4];
#pragma unroll
      for (int i = 0; i < 4; ++i)
        av[i] = *(const float4*)&As[(ty + 16 * i) * 130 + h * 32 + k0];
#pragma unroll
      for (int kk = 0; kk < 4; ++kk) {
        float4 w0 = *(const float4*)&Ws[(k0 + kk) * 128 + tx * 4];
        float4 w1 = *(const float4*)&Ws[(k0 + kk) * 128 + 64 + tx * 4];
#pragma unroll
        for (int i = 0; i < 4; ++i) {
          float s = ((const float*)&av[i])[kk];
          acc[i][0] += s * w0.x; acc[i][1] += s * w0.y;
          acc[i][2] += s * w0.z; acc[i][3] += s * w0.w;
          acc[i][4] += s * w1.x; acc[i][5] += s * w1.y;
          acc[i][6] += s * w1.z; acc[i][7] += s * w1.w;
        }
      }
    }
    if (h < 3) {
      __syncthreads();                        // drain compute before restage
#pragma unroll
      for (int l = 0; l < 4; ++l) {
        int i2 = t + l * 256;
        int kr = i2 >> 5, c4 = i2 & 31;
        *(float4*)&Ws[kr * 128 + c4 * 4] = pre[l];
      }
    }
  }

  // h1 = relu(acc + b1) -> As ; W2 chunk 0 (from pre) -> Ws
  float4 pre2[4];                             // prefetch W2 rows [64,128)
#pragma unroll
  for (int l = 0; l < 4; ++l) {
    int i2 = t + l * 256;
    int kr = i2 >> 4, c4 = i2 & 15;
    pre2[l] = *(const float4*)(W2a + (size_t)(64 + kr) * H2_ + c4 * 4);
  }
  {
    const float* b1a = b1 + (size_t)a * H1_;
    float4 bv0 = *(const float4*)(b1a + tx * 4);
    float4 bv1 = *(const float4*)(b1a + 64 + tx * 4);
    __syncthreads();                          // drain h==3 compute
#pragma unroll
    for (int i = 0; i < 4; ++i) {
      int r = ty + 16 * i;
      float4 h0, h1v;
      h0.x  = fmaxf(acc[i][0] + bv0.x, 0.f);
      h0.y  = fmaxf(acc[i][1] + bv0.y, 0.f);
      h0.z  = fmaxf(acc[i][2] + bv0.z, 0.f);
      h0.w  = fmaxf(acc[i][3] + bv0.w, 0.f);
      h1v.x = fmaxf(acc[i][4] + bv1.x, 0.f);
      h1v.y = fmaxf(acc[i][5] + bv1.y, 0.f);
      h1v.z = fmaxf(acc[i][6] + bv1.z, 0.f);
      h1v.w = fmaxf(acc[i][7] + bv1.w, 0.f);
      *(float4*)&As[r * 130 + tx * 4]      = h0;
      *(float4*)&As[r * 130 + 64 + tx * 4] = h1v;
    }
#pragma unroll
    for (int l = 0; l < 4; ++l) {             // W2 chunk 0 from pre
      int i2 = t + l * 256;
      int kr = i2 >> 4, c4 = i2 & 15;
      *(float4*)&Ws[kr * 64 + c4 * 4] = pre[l];
    }
    __syncthreads();
  }

  // layer 2: [64x128]@[128x64] in two 64-row chunks, thread tile 4x4
  float acc2[4][4];
#pragma unroll
  for (int i = 0; i < 4; ++i)
#pragma unroll
    for (int j = 0; j < 4; ++j) acc2[i][j] = 0.f;
  float4 pW3; bool hasW3 = (t < 128);
  for (int h2 = 0; h2 < 2; ++h2) {
    for (int k0 = 0; k0 < 64; k0 += 4) {
      float4 av[4];
#pragma unroll
      for (int i = 0; i < 4; ++i)
        av[i] = *(const float4*)&As[(ty + 16 * i) * 130 + h2 * 64 + k0];
#pragma unroll
      for (int kk = 0; kk < 4; ++kk) {
        float4 w = *(const float4*)&Ws[(k0 + kk) * 64 + tx * 4];
#pragma unroll
        for (int i = 0; i < 4; ++i) {
          float s = ((const float*)&av[i])[kk];
          acc2[i][0] += s * w.x; acc2[i][1] += s * w.y;
          acc2[i][2] += s * w.z; acc2[i][3] += s * w.w;
        }
      }
    }
    if (h2 == 0) {
      if (hasW3)                              // prefetch W3 (overlaps barrier)
        pW3 = *(const float4*)(W3 + (size_t)a * (H2_ * ACT_) + t * 4);
      __syncthreads();                        // drain chunk-0 compute
#pragma unroll
      for (int l = 0; l < 4; ++l) {           // W2 chunk 1 from pre2
        int i2 = t + l * 256;
        int kr = i2 >> 4, c4 = i2 & 15;
        *(float4*)&Ws[kr * 64 + c4 * 4] = pre2[l];
      }
      __syncthreads();
    }
  }

  // h2 = relu(acc2 + b2) -> As cols 0..63 ; W3 -> Ws
  {
    const float* b2a = b2 + (size_t)a * H2_;
    float4 b2v = *(const float4*)(b2a + tx * 4);
    __syncthreads();                          // drain chunk-1 compute
#pragma unroll
    for (int i = 0; i < 4; ++i) {
      int r = ty + 16 * i;
      float4 hv;
      hv.x = fmaxf(acc2[i][0] + b2v.x, 0.f);
      hv.y = fmaxf(acc2[i][1] + b2v.y, 0.f);
      hv.z = fmaxf(acc2[i][2] + b2v.z, 0.f);
      hv.w = fmaxf(acc2[i][3] + b2v.w, 0.f);
      *(float4*)&As[r * 130 + tx * 4] = hv;
    }
    if (hasW3) *(float4*)&Ws[t * 4] = pW3;
    __syncthreads();
  }

  // layer 3 + max/argmax: 4 threads per row (16-k slices), shfl combine
  {
    int r = t >> 2, qt = t & 3;
    float q[8];
#pragma unroll
    for (int c = 0; c < 8; ++c) q[c] = 0.f;
#pragma unroll
    for (int k4 = 0; k4 < 4; ++k4) {
      float4 av = *(const float4*)&As[r * 130 + qt * 16 + k4 * 4];
#pragma unroll
      for (int kk = 0; kk < 4; ++kk) {
        int k = qt * 16 + k4 * 4 + kk;
        float s = ((const float*)&av)[kk];
        float4 w0 = *(const float4*)&Ws[k * 8];
        float4 w1 = *(const float4*)&Ws[k * 8 + 4];
        q[0] += s * w0.x; q[1] += s * w0.y; q[2] += s * w0.z; q[3] += s * w0.w;
        q[4] += s * w1.x; q[5] += s * w1.y; q[6] += s * w1.z; q[7] += s * w1.w;
      }
    }
#pragma unroll
    for (int c = 0; c < 8; ++c) q[c] += __shfl_xor(q[c], 1);
#pragma unroll
    for (int c = 0; c < 8; ++c) q[c] += __shfl_xor(q[c], 2);
    if (qt == 0) {
      const float* b3a = b3 + (size_t)a * ACT_;
      float best = -1e30f; int arg = 0;
#pragma unroll
      for (int c = 0; c < 8; ++c) {
        float v = q[c] + b3a[c];
        if (v > best) { best = v; arg = c; }   // strict > keeps first max
      }
      size_t bidx = (size_t)(b0 + r) * A_ + a;
      agent_qs[bidx]    = best;
      actions_out[bidx] = (float)arg;
    }
  }
}

// --------- bf16 MFMA GEMM (m97 recipe): C = S @ Wh1 (+bh1, abs) --------------
// 1056 blocks; bijective XCD swizzle (1056 = 8*132).
__global__ __launch_bounds__(256) void gemm_kernel(
    const unsigned short* __restrict__ Abf,   // [4096][4096] states bf16
    const unsigned short* __restrict__ BT,    // [4096][4096] Wh1^T bf16
    const unsigned short* __restrict__ BTs,   // [128][4096] [Whb|Whf|Wv1|0]^T
    const float* __restrict__ bh1,
    unsigned short* __restrict__ w1abs,       // [4096][4096] bf16
    float* __restrict__ Ssmall) {             // [4096][128] fp32
  const int K = 4096;
  __shared__ unsigned short At[128 * 32];  // 8 KB
  __shared__ unsigned short Bt[128 * 32];  // 8 KB
  int t = threadIdx.x;
  int lane = t & 63, wv = t >> 6;
  int swz = (blockIdx.x & 7) * 132 + (blockIdx.x >> 3);   // bijective, 8 XCDs
  int bx = swz & 31, by = swz >> 5;
  bool small = (by == 32);
  const unsigned short* Bsrc = small ? BTs : (BT + (size_t)by * 128 * K);
  size_t row0 = (size_t)bx * 128;

  f32x4 acc[4][4] = {};
  int quad = lane >> 4, l16 = lane & 15;
  int wm = wv & 1, wn = wv >> 1;

  for (int k0 = 0; k0 < K; k0 += 32) {
#pragma unroll
    for (int is = 0; is < 2; ++is) {
      int idx2 = t + is * 256;       // 0..511 16B-chunks per tile
      int row = idx2 >> 2;
      int ko  = (idx2 & 3) * 8;
      const unsigned short* ga = Abf + (row0 + row) * (size_t)K + k0 + ko;
      const unsigned short* gb = Bsrc + (size_t)row * K + k0 + ko;
      unsigned short* la = &At[(size_t)(is * 256 + wv * 64) * 8];
      unsigned short* lb = &Bt[(size_t)(is * 256 + wv * 64) * 8];
      __builtin_amdgcn_global_load_lds(
          (const __attribute__((address_space(1))) void*)ga,
          (__attribute__((address_space(3))) void*)la, 16, 0, 0);
      __builtin_amdgcn_global_load_lds(
          (const __attribute__((address_space(1))) void*)gb,
          (__attribute__((address_space(3))) void*)lb, 16, 0, 0);
    }
    __syncthreads();
    bf16x8 af[4], bfr[4];
#pragma unroll
    for (int i = 0; i < 4; ++i) {
      int m = wm * 64 + i * 16 + l16;
      af[i] = *(const bf16x8*)&At[m * 32 + quad * 8];
      int n = wn * 64 + i * 16 + l16;
      bfr[i] = *(const bf16x8*)&Bt[n * 32 + quad * 8];
    }
#pragma unroll
    for (int i = 0; i < 4; ++i)
#pragma unroll
      for (int j = 0; j < 4; ++j)
        acc[i][j] = __builtin_amdgcn_mfma_f32_16x16x32_bf16(af[i], bfr[j],
                                                            acc[i][j], 0, 0, 0);
    __syncthreads();
  }

  // epilogue: C row=(lane>>4)*4+reg, col=lane&15 [m89-verified]
#pragma unroll
  for (int i = 0; i < 4; ++i) {
#pragma unroll
    for (int j = 0; j < 4; ++j) {
#pragma unroll
      for (int reg = 0; reg < 4; ++reg) {
        int m = wm * 64 + i * 16 + quad * 4 + reg;
        int n = wn * 64 + j * 16 + l16;
        size_t gr = row0 + m;
        float v = acc[i][j][reg];
        if (!small) {
          int gc = by * 128 + n;
          w1abs[gr * 4096 + gc] = f2bf(fabsf(v + bh1[gc]));
        } else {
          Ssmall[gr * 128 + n] = v;   // raw; biases added in mixer
        }
      }
    }
  }
}

// ---------------- mixer: 256 threads = 4 batch rows (1 wave each) ------------
__global__ __launch_bounds__(256) void mixer_kernel(
    const float* __restrict__ qs, const unsigned short* __restrict__ w1abs,
    const float* __restrict__ Ssmall, const float* __restrict__ bhb,
    const float* __restrict__ bhf, const float* __restrict__ bv1,
    const float* __restrict__ Wv2, const float* __restrict__ bv2,
    float* __restrict__ out_q) {
  int b = blockIdx.x * 4 + (threadIdx.x >> 6);
  int l = threadIdx.x & 63;
  int e = l & 31, g = l >> 5;
  const unsigned short* wrow = w1abs + (size_t)b * 4096;
  const float* qrow = qs + (size_t)b * 128;
  float z = 0.f;
  for (int a0 = g; a0 < 128; a0 += 2)
    z += qrow[a0] * bf2f(wrow[a0 * 32 + e]);   // w1 already |.+bh1|
  z += __shfl_down(z, 32);
  float total = 0.f;
  if (g == 0) {
    float sb = Ssmall[(size_t)b * 128 + e]      + bhb[e];
    float sf = Ssmall[(size_t)b * 128 + 32 + e] + bhf[e];
    float sv = Ssmall[(size_t)b * 128 + 64 + e] + bv1[e];
    float pre = z + sb;
    float hidden = pre > 0.f ? pre : expm1f(pre);      // elu, alpha=1
    total = hidden * fabsf(sf) + fmaxf(sv, 0.f) * Wv2[e];
  }
#pragma unroll
  for (int d = 1; d < 32; d <<= 1) total += __shfl_xor(total, d);
  if (l == 0) out_q[b] = total + bv2[0];
}

extern "C" void kernel_launch(void* const* d_in, const int* in_sizes, int n_in,
                              void* d_out, int out_size, void* d_ws, size_t ws_size,
                              hipStream_t stream) {
  const float* obs    = (const float*)d_in[0];
  const float* states = (const float*)d_in[1];
  const float* W1  = (const float*)d_in[2];
  const float* b1  = (const float*)d_in[3];
  const float* W2  = (const float*)d_in[4];
  const float* b2  = (const float*)d_in[5];
  const float* W3  = (const float*)d_in[6];
  const float* b3  = (const float*)d_in[7];
  const float* Wh1 = (const float*)d_in[8];
  const float* bh1 = (const float*)d_in[9];
  const float* Whb = (const float*)d_in[10];
  const float* bhb = (const float*)d_in[11];
  const float* Whf = (const float*)d_in[12];
  const float* bhf = (const float*)d_in[13];
  const float* Wv1 = (const float*)d_in[14];
  const float* bv1 = (const float*)d_in[15];
  const float* Wv2 = (const float*)d_in[16];
  const float* bv2 = (const float*)d_in[17];

  float* out_q   = (float*)d_out;
  float* out_act = out_q + BS_;

  char* ws = (char*)d_ws;
  unsigned short* Sbf   = (unsigned short*)(ws);               // 33,554,432 B
  unsigned short* Wh1T  = (unsigned short*)(ws + 33554432);    // 33,554,432 B
  unsigned short* WsmT  = (unsigned short*)(ws + 67108864);    //  1,048,576 B
  unsigned short* w1abs = (unsigned short*)(ws + 68157440);    // 33,554,432 B
  float* Ssmall = (float*)(ws + 101711872);                    //  2,097,152 B
  float* aqs    = (float*)(ws + 103809024);                    //  2,097,152 B
  (void)ws_size; (void)in_sizes; (void)n_in; (void)out_size;   // total ~106 MB

  prep_kernel<<<18944, 256, 0, stream>>>(states, Sbf, Wh1, Wh1T, Whb, Whf, Wv1, WsmT);
  mlp_kernel<<<8192, 256, 0, stream>>>(obs, W1, b1, W2, b2, W3, b3, aqs, out_act);
  gemm_kernel<<<1056, 256, 0, stream>>>(Sbf, Wh1T, WsmT, bh1, w1abs, Ssmall);
  mixer_kernel<<<1024, 256, 0, stream>>>(aqs, w1abs, Ssmall, bhb, bhf, bv1, Wv2, bv2, out_q);
}

// Round 4
// 1089.932 us; speedup vs baseline: 2.0361x; 2.0361x over previous
//
#include <hip/hip_runtime.h>
#include <cstdint>
#include <cstddef>

#define BS_  4096
#define A_   128
#define OBS_ 128
#define ACT_ 8
#define SD_  4096
#define E_   32
#define H1_  128
#define H2_  64
#define NJ_  4096  // E_*A_

typedef __attribute__((ext_vector_type(8))) short bf16x8;
typedef __attribute__((ext_vector_type(4))) float f32x4;

__device__ __forceinline__ unsigned short f2bf(float f) {
  uint32_t u = __builtin_bit_cast(uint32_t, f);
  u += 0x7fffu + ((u >> 16) & 1u);   // RNE
  return (unsigned short)(u >> 16);
}
__device__ __forceinline__ float bf2f(unsigned short s) {
  return __builtin_bit_cast(float, (uint32_t)s << 16);
}

// ============ prep: Wh1 transpose + states->bf16 + small-W pack, one launch ==
// blocks [0,16384): transpose Wh1 [4096][4096] fp32 -> Wh1T bf16
// blocks [16384,18432): states fp32 -> bf16 flat
// blocks [18432,18944): pack [Whb|Whf|Wv1|0]^T -> WsmT [128][4096] bf16
__global__ __launch_bounds__(256) void prep_kernel(
    const float* __restrict__ states, unsigned short* __restrict__ Sbf,
    const float* __restrict__ Wh1, unsigned short* __restrict__ Wh1T,
    const float* __restrict__ Whb, const float* __restrict__ Whf,
    const float* __restrict__ Wv1, unsigned short* __restrict__ WsmT) {
  __shared__ float tile[32][33];
  int bid = blockIdx.x;
  int t = threadIdx.x;
  if (bid < 16384) {
    int tx = t & 31, ty = t >> 5;
    int c0 = (bid & 127) * 32, r0 = (bid >> 7) * 32;
#pragma unroll
    for (int rr = ty; rr < 32; rr += 8)
      tile[rr][tx] = Wh1[(size_t)(r0 + rr) * NJ_ + c0 + tx];
    __syncthreads();
#pragma unroll
    for (int rr = ty; rr < 32; rr += 8)
      Wh1T[(size_t)(c0 + rr) * SD_ + r0 + tx] = f2bf(tile[tx][rr]);
  } else if (bid < 18432) {
    // 2048 blocks * 256 thr * 8 float4 == BS_*SD_/4 exactly
    int i = (bid - 16384) * 256 + t;
    const int stride = 2048 * 256;
#pragma unroll
    for (int l = 0; l < 8; ++l, i += stride) {
      float4 v = ((const float4*)states)[i];
      ushort4 o;
      o.x = f2bf(v.x); o.y = f2bf(v.y); o.z = f2bf(v.z); o.w = f2bf(v.w);
      ((ushort4*)Sbf)[i] = o;
    }
  } else {
    int k = bid - 18432;            // 0..511
    int s = k >> 7;                 // 0:Whb 1:Whf 2:Wv1 3:zero
    int r0 = (k & 127) * 32;
    int tx = t & 31, ty = t >> 5;
    if (s == 3) {
#pragma unroll
      for (int rr = ty; rr < 32; rr += 8)
        WsmT[(size_t)(96 + rr) * SD_ + r0 + tx] = 0;
    } else {
      const float* src = (s == 0) ? Whb : ((s == 1) ? Whf : Wv1);
#pragma unroll
      for (int rr = ty; rr < 32; rr += 8)
        tile[rr][tx] = src[(size_t)(r0 + rr) * E_ + tx];
      __syncthreads();
#pragma unroll
      for (int rr = ty; rr < 32; rr += 8)
        WsmT[(size_t)(s * 32 + rr) * SD_ + r0 + tx] = f2bf(tile[tx][rr]);
    }
  }
}

// ---------------- per-agent MLP (fp32 exact; argmax-critical) ----------------
// EXACT baseline (harness-verified, ~480 us standalone): 256 threads,
// 1 agent x 64 batch rows, thread tile 4x8. LDS 66048 B -> 2 blocks/CU
// (8 waves) -- that TLP hides stage latency; do NOT register-prefetch here
// (round-3: VGPR 112->228, spills, 12% occupancy, 1543 us).
__global__ __launch_bounds__(256) void mlp_kernel(
    const float* __restrict__ obs,
    const float* __restrict__ W1, const float* __restrict__ b1,
    const float* __restrict__ W2, const float* __restrict__ b2,
    const float* __restrict__ W3, const float* __restrict__ b3,
    float* __restrict__ agent_qs, float* __restrict__ actions_out) {
  __shared__ float As[64 * 130];   // 33280 B
  __shared__ float Ws[128 * 64];   // 32768 B: W1-half / W2 / W3
  int a  = blockIdx.x & (A_ - 1);
  int bt = blockIdx.x >> 7;
  int b0 = bt * 64;
  int t  = threadIdx.x;
  int tx = t & 15, ty = t >> 4;    // tx: col group (16), ty: row group (16)

  // stage obs tile [64][128] (coalesced 512B rows)
  {
    const float* src = obs + ((size_t)b0 * A_ + a) * OBS_;
#pragma unroll
    for (int l = 0; l < 8; ++l) {
      int idx = t + l * 256;
      int r = idx >> 5, c4 = idx & 31;
      float4 v = *(const float4*)(src + (size_t)r * (A_ * OBS_) + c4 * 4);
      *(float4*)&As[r * 130 + c4 * 4] = v;
    }
  }

  float acc[4][8];
#pragma unroll
  for (int i = 0; i < 4; ++i)
#pragma unroll
    for (int j = 0; j < 8; ++j) acc[i][j] = 0.f;

  const float* W1a = W1 + (size_t)a * OBS_ * H1_;
  for (int h = 0; h < 2; ++h) {
    if (h) __syncthreads();                 // drain half-0 compute before restage
#pragma unroll
    for (int l = 0; l < 8; ++l) {           // stage W1 k-half [64][128]
      int idx = t + l * 256;
      int kr = idx >> 5, c4 = idx & 31;
      *(float4*)&Ws[kr * 128 + c4 * 4] =
          *(const float4*)(W1a + (size_t)(h * 64 + kr) * H1_ + c4 * 4);
    }
    __syncthreads();
    for (int k0 = 0; k0 < 64; k0 += 4) {
      float4 av[4];
#pragma unroll
      for (int i = 0; i < 4; ++i)
        av[i] = *(const float4*)&As[(ty + 16 * i) * 130 + h * 64 + k0];
#pragma unroll
      for (int kk = 0; kk < 4; ++kk) {
        float4 w0 = *(const float4*)&Ws[(k0 + kk) * 128 + tx * 4];
        float4 w1 = *(const float4*)&Ws[(k0 + kk) * 128 + 64 + tx * 4];
#pragma unroll
        for (int i = 0; i < 4; ++i) {
          float s = ((const float*)&av[i])[kk];
          acc[i][0] += s * w0.x; acc[i][1] += s * w0.y;
          acc[i][2] += s * w0.z; acc[i][3] += s * w0.w;
          acc[i][4] += s * w1.x; acc[i][5] += s * w1.y;
          acc[i][6] += s * w1.z; acc[i][7] += s * w1.w;
        }
      }
    }
  }

  // h1 = relu(acc + b1) -> As ; stage W2 [128][64]
  {
    const float* b1a = b1 + (size_t)a * H1_;
    float4 bv0 = *(const float4*)(b1a + tx * 4);
    float4 bv1 = *(const float4*)(b1a + 64 + tx * 4);
    __syncthreads();
#pragma unroll
    for (int i = 0; i < 4; ++i) {
      int r = ty + 16 * i;
      float4 h0, h1v;
      h0.x  = fmaxf(acc[i][0] + bv0.x, 0.f);
      h0.y  = fmaxf(acc[i][1] + bv0.y, 0.f);
      h0.z  = fmaxf(acc[i][2] + bv0.z, 0.f);
      h0.w  = fmaxf(acc[i][3] + bv0.w, 0.f);
      h1v.x = fmaxf(acc[i][4] + bv1.x, 0.f);
      h1v.y = fmaxf(acc[i][5] + bv1.y, 0.f);
      h1v.z = fmaxf(acc[i][6] + bv1.z, 0.f);
      h1v.w = fmaxf(acc[i][7] + bv1.w, 0.f);
      *(float4*)&As[r * 130 + tx * 4]      = h0;
      *(float4*)&As[r * 130 + 64 + tx * 4] = h1v;
    }
    const float* W2a = W2 + (size_t)a * H1_ * H2_;
#pragma unroll
    for (int l = 0; l < 8; ++l) {
      int idx = t + l * 256;
      int kr = idx >> 4, c4 = idx & 15;
      *(float4*)&Ws[kr * 64 + c4 * 4] =
          *(const float4*)(W2a + (size_t)kr * H2_ + c4 * 4);
    }
    __syncthreads();
  }

  // layer 2: [64x128]@[128x64], thread tile 4x4 (cols 4tx..4tx+3)
  float acc2[4][4];
#pragma unroll
  for (int i = 0; i < 4; ++i)
#pragma unroll
    for (int j = 0; j < 4; ++j) acc2[i][j] = 0.f;
  for (int k0 = 0; k0 < 128; k0 += 4) {
    float4 av[4];
#pragma unroll
    for (int i = 0; i < 4; ++i)
      av[i] = *(const float4*)&As[(ty + 16 * i) * 130 + k0];
#pragma unroll
    for (int kk = 0; kk < 4; ++kk) {
      float4 w = *(const float4*)&Ws[(k0 + kk) * 64 + tx * 4];
#pragma unroll
      for (int i = 0; i < 4; ++i) {
        float s = ((const float*)&av[i])[kk];
        acc2[i][0] += s * w.x; acc2[i][1] += s * w.y;
        acc2[i][2] += s * w.z; acc2[i][3] += s * w.w;
      }
    }
  }

  // h2 = relu(acc2 + b2) -> As cols 0..63 ; stage W3 [64][8]
  {
    const float* b2a = b2 + (size_t)a * H2_;
    float4 b2v = *(const float4*)(b2a + tx * 4);
    __syncthreads();
#pragma unroll
    for (int i = 0; i < 4; ++i) {
      int r = ty + 16 * i;
      float4 hv;
      hv.x = fmaxf(acc2[i][0] + b2v.x, 0.f);
      hv.y = fmaxf(acc2[i][1] + b2v.y, 0.f);
      hv.z = fmaxf(acc2[i][2] + b2v.z, 0.f);
      hv.w = fmaxf(acc2[i][3] + b2v.w, 0.f);
      *(float4*)&As[r * 130 + tx * 4] = hv;
    }
    if (t < 128)
      *(float4*)&Ws[t * 4] =
          *(const float4*)(W3 + (size_t)a * (H2_ * ACT_) + t * 4);
    __syncthreads();
  }

  // layer 3 + max/argmax: 4 threads per row (16-k slices), shfl combine
  {
    int r = t >> 2, qt = t & 3;
    float q[8];
#pragma unroll
    for (int c = 0; c < 8; ++c) q[c] = 0.f;
#pragma unroll
    for (int k4 = 0; k4 < 4; ++k4) {
      float4 av = *(const float4*)&As[r * 130 + qt * 16 + k4 * 4];
#pragma unroll
      for (int kk = 0; kk < 4; ++kk) {
        int k = qt * 16 + k4 * 4 + kk;
        float s = ((const float*)&av)[kk];
        float4 w0 = *(const float4*)&Ws[k * 8];
        float4 w1 = *(const float4*)&Ws[k * 8 + 4];
        q[0] += s * w0.x; q[1] += s * w0.y; q[2] += s * w0.z; q[3] += s * w0.w;
        q[4] += s * w1.x; q[5] += s * w1.y; q[6] += s * w1.z; q[7] += s * w1.w;
      }
    }
#pragma unroll
    for (int c = 0; c < 8; ++c) q[c] += __shfl_xor(q[c], 1);
#pragma unroll
    for (int c = 0; c < 8; ++c) q[c] += __shfl_xor(q[c], 2);
    if (qt == 0) {
      const float* b3a = b3 + (size_t)a * ACT_;
      float best = -1e30f; int arg = 0;
#pragma unroll
      for (int c = 0; c < 8; ++c) {
        float v = q[c] + b3a[c];
        if (v > best) { best = v; arg = c; }   // strict > keeps first max
      }
      size_t bidx = (size_t)(b0 + r) * A_ + a;
      agent_qs[bidx]    = best;
      actions_out[bidx] = (float)arg;
    }
  }
}

// --------- bf16 MFMA GEMM (m97 recipe): C = S @ Wh1 (+bh1, abs) --------------
// 1056 blocks; bijective XCD swizzle (1056 = 8*132). Launched right after
// prep so Sbf/Wh1T are still L3-hot (mlp's 289 MB obs stream would evict).
__global__ __launch_bounds__(256) void gemm_kernel(
    const unsigned short* __restrict__ Abf,   // [4096][4096] states bf16
    const unsigned short* __restrict__ BT,    // [4096][4096] Wh1^T bf16
    const unsigned short* __restrict__ BTs,   // [128][4096] [Whb|Whf|Wv1|0]^T
    const float* __restrict__ bh1,
    unsigned short* __restrict__ w1abs,       // [4096][4096] bf16
    float* __restrict__ Ssmall) {             // [4096][128] fp32
  const int K = 4096;
  __shared__ unsigned short At[128 * 32];  // 8 KB
  __shared__ unsigned short Bt[128 * 32];  // 8 KB
  int t = threadIdx.x;
  int lane = t & 63, wv = t >> 6;
  int swz = (blockIdx.x & 7) * 132 + (blockIdx.x >> 3);   // bijective, 8 XCDs
  int bx = swz & 31, by = swz >> 5;
  bool small = (by == 32);
  const unsigned short* Bsrc = small ? BTs : (BT + (size_t)by * 128 * K);
  size_t row0 = (size_t)bx * 128;

  f32x4 acc[4][4] = {};
  int quad = lane >> 4, l16 = lane & 15;
  int wm = wv & 1, wn = wv >> 1;

  for (int k0 = 0; k0 < K; k0 += 32) {
#pragma unroll
    for (int is = 0; is < 2; ++is) {
      int idx2 = t + is * 256;       // 0..511 16B-chunks per tile
      int row = idx2 >> 2;
      int ko  = (idx2 & 3) * 8;
      const unsigned short* ga = Abf + (row0 + row) * (size_t)K + k0 + ko;
      const unsigned short* gb = Bsrc + (size_t)row * K + k0 + ko;
      unsigned short* la = &At[(size_t)(is * 256 + wv * 64) * 8];
      unsigned short* lb = &Bt[(size_t)(is * 256 + wv * 64) * 8];
      __builtin_amdgcn_global_load_lds(
          (const __attribute__((address_space(1))) void*)ga,
          (__attribute__((address_space(3))) void*)la, 16, 0, 0);
      __builtin_amdgcn_global_load_lds(
          (const __attribute__((address_space(1))) void*)gb,
          (__attribute__((address_space(3))) void*)lb, 16, 0, 0);
    }
    __syncthreads();
    bf16x8 af[4], bfr[4];
#pragma unroll
    for (int i = 0; i < 4; ++i) {
      int m = wm * 64 + i * 16 + l16;
      af[i] = *(const bf16x8*)&At[m * 32 + quad * 8];
      int n = wn * 64 + i * 16 + l16;
      bfr[i] = *(const bf16x8*)&Bt[n * 32 + quad * 8];
    }
#pragma unroll
    for (int i = 0; i < 4; ++i)
#pragma unroll
      for (int j = 0; j < 4; ++j)
        acc[i][j] = __builtin_amdgcn_mfma_f32_16x16x32_bf16(af[i], bfr[j],
                                                            acc[i][j], 0, 0, 0);
    __syncthreads();
  }

  // epilogue: C row=(lane>>4)*4+reg, col=lane&15 [m89-verified]
#pragma unroll
  for (int i = 0; i < 4; ++i) {
#pragma unroll
    for (int j = 0; j < 4; ++j) {
#pragma unroll
      for (int reg = 0; reg < 4; ++reg) {
        int m = wm * 64 + i * 16 + quad * 4 + reg;
        int n = wn * 64 + j * 16 + l16;
        size_t gr = row0 + m;
        float v = acc[i][j][reg];
        if (!small) {
          int gc = by * 128 + n;
          w1abs[gr * 4096 + gc] = f2bf(fabsf(v + bh1[gc]));
        } else {
          Ssmall[gr * 128 + n] = v;   // raw; biases added in mixer
        }
      }
    }
  }
}

// ---------------- mixer: 256 threads = 4 batch rows (1 wave each) ------------
__global__ __launch_bounds__(256) void mixer_kernel(
    const float* __restrict__ qs, const unsigned short* __restrict__ w1abs,
    const float* __restrict__ Ssmall, const float* __restrict__ bhb,
    const float* __restrict__ bhf, const float* __restrict__ bv1,
    const float* __restrict__ Wv2, const float* __restrict__ bv2,
    float* __restrict__ out_q) {
  int b = blockIdx.x * 4 + (threadIdx.x >> 6);
  int l = threadIdx.x & 63;
  int e = l & 31, g = l >> 5;
  const unsigned short* wrow = w1abs + (size_t)b * 4096;
  const float* qrow = qs + (size_t)b * 128;
  float z = 0.f;
  for (int a0 = g; a0 < 128; a0 += 2)
    z += qrow[a0] * bf2f(wrow[a0 * 32 + e]);   // w1 already |.+bh1|
  z += __shfl_down(z, 32);
  float total = 0.f;
  if (g == 0) {
    float sb = Ssmall[(size_t)b * 128 + e]      + bhb[e];
    float sf = Ssmall[(size_t)b * 128 + 32 + e] + bhf[e];
    float sv = Ssmall[(size_t)b * 128 + 64 + e] + bv1[e];
    float pre = z + sb;
    float hidden = pre > 0.f ? pre : expm1f(pre);      // elu, alpha=1
    total = hidden * fabsf(sf) + fmaxf(sv, 0.f) * Wv2[e];
  }
#pragma unroll
  for (int d = 1; d < 32; d <<= 1) total += __shfl_xor(total, d);
  if (l == 0) out_q[b] = total + bv2[0];
}

extern "C" void kernel_launch(void* const* d_in, const int* in_sizes, int n_in,
                              void* d_out, int out_size, void* d_ws, size_t ws_size,
                              hipStream_t stream) {
  const float* obs    = (const float*)d_in[0];
  const float* states = (const float*)d_in[1];
  const float* W1  = (const float*)d_in[2];
  const float* b1  = (const float*)d_in[3];
  const float* W2  = (const float*)d_in[4];
  const float* b2  = (const float*)d_in[5];
  const float* W3  = (const float*)d_in[6];
  const float* b3  = (const float*)d_in[7];
  const float* Wh1 = (const float*)d_in[8];
  const float* bh1 = (const float*)d_in[9];
  const float* Whb = (const float*)d_in[10];
  const float* bhb = (const float*)d_in[11];
  const float* Whf = (const float*)d_in[12];
  const float* bhf = (const float*)d_in[13];
  const float* Wv1 = (const float*)d_in[14];
  const float* bv1 = (const float*)d_in[15];
  const float* Wv2 = (const float*)d_in[16];
  const float* bv2 = (const float*)d_in[17];

  float* out_q   = (float*)d_out;
  float* out_act = out_q + BS_;

  char* ws = (char*)d_ws;
  unsigned short* Sbf   = (unsigned short*)(ws);               // 33,554,432 B
  unsigned short* Wh1T  = (unsigned short*)(ws + 33554432);    // 33,554,432 B
  unsigned short* WsmT  = (unsigned short*)(ws + 67108864);    //  1,048,576 B
  unsigned short* w1abs = (unsigned short*)(ws + 68157440);    // 33,554,432 B
  float* Ssmall = (float*)(ws + 101711872);                    //  2,097,152 B
  float* aqs    = (float*)(ws + 103809024);                    //  2,097,152 B
  (void)ws_size; (void)in_sizes; (void)n_in; (void)out_size;   // total ~106 MB

  prep_kernel<<<18944, 256, 0, stream>>>(states, Sbf, Wh1, Wh1T, Whb, Whf, Wv1, WsmT);
  gemm_kernel<<<1056, 256, 0, stream>>>(Sbf, Wh1T, WsmT, bh1, w1abs, Ssmall);
  mlp_kernel<<<8192, 256, 0, stream>>>(obs, W1, b1, W2, b2, W3, b3, aqs, out_act);
  mixer_kernel<<<1024, 256, 0, stream>>>(aqs, w1abs, Ssmall, bhb, bhf, bv1, Wv2, bv2, out_q);
}